// Round 3
// baseline (397.691 us; speedup 1.0000x reference)
//
#include <hip/hip_runtime.h>
#include <hip/hip_bf16.h>
#include <stdint.h>

#define B_SZ 4
#define T_SZ 2048
#define D_SZ 1024

constexpr int BM = 32;     // Q rows per tile
constexpr int BN = 64;     // KV rows per s-tile
constexpr int NTH = 512;   // 8 waves

typedef short bf16x8 __attribute__((ext_vector_type(8)));
typedef float f32x4 __attribute__((ext_vector_type(4)));
typedef int i32x4 __attribute__((ext_vector_type(4)));
typedef unsigned short ushort8 __attribute__((ext_vector_type(8)));

__device__ __forceinline__ uint32_t sbf(uint32_t xu, uint32_t su) {
  return 0x3F80u | (((xu ^ su) >> 16) & 0x8000u);
}

__device__ __forceinline__ ushort f2bf(float f) {  // RNE f32->bf16
  uint32_t u = __float_as_uint(f);
  return (ushort)((u + 0x7FFFu + ((u >> 16) & 1u)) >> 16);
}

// ============================ PREP KERNEL =============================
// Qb,Kb: int8 sign(x)*sign(bq/bk) in [B][T][D].  Vt: bf16 x*sign(bv) in [B][D][T].
__global__ __launch_bounds__(256) void prep_kernel(
    const float* __restrict__ x, const float* __restrict__ bvq,
    const float* __restrict__ bvk, const float* __restrict__ bvv,
    char* __restrict__ Qb, char* __restrict__ Kb, ushort* __restrict__ Vt) {
  __shared__ ushort vt[64][72];
  const int bid = blockIdx.x;
  const int dt = bid & 15;         // 16 d-tiles of 64
  const int tt = (bid >> 4) & 31;  // 32 t-tiles of 64
  const int b = bid >> 9;
  const int t0 = tt * 64, d0 = dt * 64;
  const int tid = threadIdx.x;

#pragma unroll
  for (int p = 0; p < 4; ++p) {
    const int row = p * 16 + (tid >> 4);
    const int c4 = tid & 15;
    const size_t idx = ((size_t)(b * T_SZ + t0 + row)) * D_SZ + d0 + c4 * 4;
    float4 v = *(const float4*)(x + idx);
    float4 q = *(const float4*)(bvq + d0 + c4 * 4);
    float4 k = *(const float4*)(bvk + d0 + c4 * 4);
    float4 s = *(const float4*)(bvv + d0 + c4 * 4);
    uint32_t xu[4] = {__float_as_uint(v.x), __float_as_uint(v.y),
                      __float_as_uint(v.z), __float_as_uint(v.w)};
    uint32_t qu[4] = {__float_as_uint(q.x), __float_as_uint(q.y),
                      __float_as_uint(q.z), __float_as_uint(q.w)};
    uint32_t ku[4] = {__float_as_uint(k.x), __float_as_uint(k.y),
                      __float_as_uint(k.z), __float_as_uint(k.w)};
    uint32_t su[4] = {__float_as_uint(s.x), __float_as_uint(s.y),
                      __float_as_uint(s.z), __float_as_uint(s.w)};
    uint32_t qw = 0, kw = 0;
#pragma unroll
    for (int j = 0; j < 4; ++j) {
      uint32_t qb = ((xu[j] ^ qu[j]) & 0x80000000u) ? 0xFFu : 0x01u;
      uint32_t kb = ((xu[j] ^ ku[j]) & 0x80000000u) ? 0xFFu : 0x01u;
      qw |= qb << (8 * j);
      kw |= kb << (8 * j);
      vt[row][c4 * 4 + j] = f2bf(__uint_as_float(xu[j] ^ (su[j] & 0x80000000u)));
    }
    *(uint32_t*)(Qb + idx) = qw;
    *(uint32_t*)(Kb + idx) = kw;
  }
  __syncthreads();
#pragma unroll
  for (int p = 0; p < 2; ++p) {
    const int dr = p * 32 + (tid >> 3);
    const int tc = tid & 7;
    ushort8 o;
#pragma unroll
    for (int j = 0; j < 8; ++j) o[j] = vt[tc * 8 + j][dr];
    *(ushort8*)(Vt + ((size_t)(b * D_SZ + d0 + dr)) * T_SZ + t0 + tc * 8) = o;
  }
}

// ============================ MAIN KERNEL =============================
// block = (b, tile-pair, 256-wide d-slice). Computes S fully (QK redundant
// across the 4 d-slices — cheap i8 MFMA), PV + store only its d-slice.
// Pair (pr, 63-pr) makes causal work per block constant. No atomics.
__global__ __launch_bounds__(NTH, 4) void attn_main(
    const char* __restrict__ Qb, const char* __restrict__ Kb,
    const ushort* __restrict__ Vt, float* __restrict__ out) {
  __shared__ __align__(16) unsigned char Qs[BM][1040];  // 33.3 KB
  __shared__ __align__(16) ushort Ps[2][BM][72];        // 9.2 KB (dbuf)

  const int tid = threadIdx.x;
  const int lane = tid & 63;
  const int w = tid >> 6;
  const int rg = w >> 2;  // 0..1 : 16 q-row group
  const int cg = w & 3;   // 0..3 : 16 s-cols (QK) / 64 d-cols (PV)
  const int l15 = lane & 15;
  const int l4 = lane >> 4;

  const int bid = blockIdx.x;
  const int ds = bid & 3;          // d-slice of 256
  const int pr = (bid >> 2) & 31;  // tile pair
  const int b = bid >> 7;

  for (int half = 0; half < 2; ++half) {
    const int ti = half ? (63 - pr) : pr;
    const int t0 = ti * BM;

    __syncthreads();  // prior-tile Qs/Ps readers done
    {
      const int row = tid >> 4;
      const int c = (tid & 15) * 64;
      const uint4* src =
          (const uint4*)(Qb + ((size_t)(b * T_SZ + t0 + row)) * D_SZ + c);
      uint4 a0 = src[0], a1 = src[1], a2 = src[2], a3 = src[3];
      *(uint4*)&Qs[row][c] = a0;
      *(uint4*)&Qs[row][c + 16] = a1;
      *(uint4*)&Qs[row][c + 32] = a2;
      *(uint4*)&Qs[row][c + 48] = a3;
    }
    __syncthreads();

    const int nt = (t0 + BM + BN - 1) / BN;  // causal s-tile count

    f32x4 acc[4];
#pragma unroll
    for (int f = 0; f < 4; ++f) acc[f] = (f32x4){0.f, 0.f, 0.f, 0.f};

    // ---- prologue: prefetch K frags for st=0 ----
    i32x4 kreg[16];
    {
      const char* kb0 =
          Kb + ((size_t)(b * T_SZ + cg * 16 + l15)) * D_SZ + l4 * 16;
#pragma unroll
      for (int kc = 0; kc < 16; ++kc)
        kreg[kc] = *(const i32x4*)(kb0 + kc * 64);
    }

    const unsigned char* qrow = &Qs[rg * 16 + l15][l4 * 16];

    for (int st = 0; st < nt; ++st) {
      // ---- QK^T from prefetched K ----
      i32x4 sacc = (i32x4){0, 0, 0, 0};
#pragma unroll
      for (int kc = 0; kc < 16; ++kc) {
        i32x4 a = *(const i32x4*)(qrow + kc * 64);
        sacc = __builtin_amdgcn_mfma_i32_16x16x64_i8(a, kreg[kc], sacc, 0, 0, 0);
      }

      // ---- issue next s-tile's K loads (hide under sigmoid+PV) ----
      {
        const int stn = (st + 1 < nt) ? st + 1 : st;
        const char* kbn =
            Kb + ((size_t)(b * T_SZ + stn * BN + cg * 16 + l15)) * D_SZ +
            l4 * 16;
#pragma unroll
        for (int kc = 0; kc < 16; ++kc)
          kreg[kc] = *(const i32x4*)(kbn + kc * 64);
      }

      // ---- causal mask + sigmoid -> Ps[st&1] ----
      {
        const int scol = cg * 16 + l15;
        const int sg = st * BN + scol;
#pragma unroll
        for (int r = 0; r < 4; ++r) {
          const int m = rg * 16 + l4 * 4 + r;
          float p = 0.f;
          if (sg <= t0 + m) p = 1.f / (1.f + __expf(-0.125f * (float)sacc[r]));
          Ps[st & 1][m][scol] = f2bf(p);
        }
      }
      __syncthreads();  // Ps[st&1] visible (prev readers of this parity were
                        // fenced by the previous step's barrier)

      // ---- PV for this block's 256-col d-slice ----
      const ushort* vtb =
          Vt + ((size_t)(b * D_SZ + ds * 256 + cg * 64)) * T_SZ + st * BN;
#pragma unroll
      for (int kk = 0; kk < 2; ++kk) {
        bf16x8 pa = *(const bf16x8*)&Ps[st & 1][rg * 16 + l15][kk * 32 + l4 * 8];
        const ushort* vks = vtb + kk * 32 + l4 * 8;
#pragma unroll
        for (int f = 0; f < 4; ++f) {
          bf16x8 vb = *(const bf16x8*)(vks + (size_t)(f * 16 + l15) * T_SZ);
          acc[f] = __builtin_amdgcn_mfma_f32_16x16x32_bf16(pa, vb, acc[f], 0, 0, 0);
        }
      }
    }

    // ---- store this tile's d-slice (each element owned by exactly one block) ----
    float* orow = out + ((size_t)(b * T_SZ + t0)) * D_SZ + ds * 256 + cg * 64;
#pragma unroll
    for (int f = 0; f < 4; ++f) {
      const int n = f * 16 + l15;
#pragma unroll
      for (int r = 0; r < 4; ++r) {
        const int m = rg * 16 + l4 * 4 + r;
        orow[(size_t)m * D_SZ + n] = acc[f][r];
      }
    }
  }
}

// ===================== FALLBACK (if ws too small) =====================
__global__ __launch_bounds__(NTH) void hdc_attn_fallback(
    const float* __restrict__ x, const float* __restrict__ bvq,
    const float* __restrict__ bvk, const float* __restrict__ bvv,
    float* __restrict__ out) {
  __shared__ ushort Qs[BM][1032];
  __shared__ ushort Ks[BN][72];
  __shared__ ushort Ps[BM][72];
  const int tid = threadIdx.x;
  const int lane = tid & 63;
  const int w = tid >> 6;
  const int rg = w >> 2, cg = w & 3;
  const int l15 = lane & 15, l4 = lane >> 4;
  const int b = blockIdx.x >> 6;
  const int ti = blockIdx.x & 63;
  const int t0 = ti * BM;
  {
    const float4* xr = (const float4*)(x + ((size_t)b * T_SZ + t0) * D_SZ);
    const float4* bq4 = (const float4*)bvq;
#pragma unroll
    for (int i = 0; i < 16; ++i) {
      int flat4 = tid + i * NTH;
      int row = flat4 >> 8, c4 = flat4 & 255;
      float4 v = xr[row * 256 + c4];
      float4 q = bq4[c4];
      uint32_t q0 = sbf(__float_as_uint(v.x), __float_as_uint(q.x));
      uint32_t q1 = sbf(__float_as_uint(v.y), __float_as_uint(q.y));
      uint32_t q2 = sbf(__float_as_uint(v.z), __float_as_uint(q.z));
      uint32_t q3 = sbf(__float_as_uint(v.w), __float_as_uint(q.w));
      *(uint2*)&Qs[row][c4 * 4] = make_uint2(q0 | (q1 << 16), q2 | (q3 << 16));
    }
  }
  uint32_t vsign[16];
#pragma unroll
  for (int f = 0; f < 16; ++f)
    vsign[f] = __float_as_uint(bvv[cg * 256 + f * 16 + l15]) & 0x80000000u;
  f32x4 acc[16];
#pragma unroll
  for (int f = 0; f < 16; ++f) acc[f] = (f32x4){0.f, 0.f, 0.f, 0.f};
  const int nt = (t0 + BM + BN - 1) / BN;
  for (int st = 0; st < nt; ++st) {
    const int s0 = st * BN;
    f32x4 sacc = (f32x4){0.f, 0.f, 0.f, 0.f};
    for (int dc = 0; dc < D_SZ / 64; ++dc) {
      __syncthreads();
      {
        const int s = tid >> 3;
        const int c8 = (tid & 7) * 8;
        const float* xk = x + ((size_t)b * T_SZ + s0 + s) * D_SZ + dc * 64 + c8;
        const float* bk = bvk + dc * 64 + c8;
        float4 v0 = *(const float4*)xk;
        float4 v1 = *(const float4*)(xk + 4);
        float4 k0 = *(const float4*)bk;
        float4 k1 = *(const float4*)(bk + 4);
        uint32_t w0 = sbf(__float_as_uint(v0.x), __float_as_uint(k0.x)) |
                      (sbf(__float_as_uint(v0.y), __float_as_uint(k0.y)) << 16);
        uint32_t w1 = sbf(__float_as_uint(v0.z), __float_as_uint(k0.z)) |
                      (sbf(__float_as_uint(v0.w), __float_as_uint(k0.w)) << 16);
        uint32_t w2 = sbf(__float_as_uint(v1.x), __float_as_uint(k1.x)) |
                      (sbf(__float_as_uint(v1.y), __float_as_uint(k1.y)) << 16);
        uint32_t w3 = sbf(__float_as_uint(v1.z), __float_as_uint(k1.z)) |
                      (sbf(__float_as_uint(v1.w), __float_as_uint(k1.w)) << 16);
        *(uint4*)&Ks[s][c8] = make_uint4(w0, w1, w2, w3);
      }
      __syncthreads();
#pragma unroll
      for (int h = 0; h < 2; ++h) {
        bf16x8 a = *(const bf16x8*)&Qs[rg * 16 + l15][dc * 64 + h * 32 + l4 * 8];
        bf16x8 kb = *(const bf16x8*)&Ks[cg * 16 + l15][h * 32 + l4 * 8];
        sacc = __builtin_amdgcn_mfma_f32_16x16x32_bf16(a, kb, sacc, 0, 0, 0);
      }
    }
    {
      const int scol = cg * 16 + l15;
      const int sg = s0 + scol;
#pragma unroll
      for (int r = 0; r < 4; ++r) {
        const int m = rg * 16 + l4 * 4 + r;
        float p = 0.f;
        if (sg <= t0 + m) p = 1.f / (1.f + __expf(-0.125f * sacc[r]));
        Ps[m][scol] = (ushort)(__float_as_uint(p) >> 16);
      }
    }
    __syncthreads();
    const float* xv = x + ((size_t)b * T_SZ + s0) * D_SZ;
#pragma unroll
    for (int kk = 0; kk < 2; ++kk) {
      bf16x8 pa = *(const bf16x8*)&Ps[rg * 16 + l15][kk * 32 + l4 * 8];
      const float* xvs = xv + (size_t)(kk * 32 + l4 * 8) * D_SZ;
#pragma unroll
      for (int f = 0; f < 16; ++f) {
        const int n = cg * 256 + f * 16 + l15;
        const float* xn = xvs + n;
        bf16x8 vb;
#pragma unroll
        for (int i = 0; i < 8; ++i) {
          uint32_t u = __float_as_uint(xn[(size_t)i * D_SZ]) ^ vsign[f];
          vb[i] = (short)(u >> 16);
        }
        acc[f] = __builtin_amdgcn_mfma_f32_16x16x32_bf16(pa, vb, acc[f], 0, 0, 0);
      }
    }
  }
  float* orow = out + ((size_t)b * T_SZ + t0) * D_SZ;
#pragma unroll
  for (int f = 0; f < 16; ++f) {
    const int n = cg * 256 + f * 16 + l15;
#pragma unroll
    for (int r = 0; r < 4; ++r) {
      const int m = rg * 16 + l4 * 4 + r;
      orow[(size_t)m * D_SZ + n] = acc[f][r];
    }
  }
}

extern "C" void kernel_launch(void* const* d_in, const int* in_sizes, int n_in,
                              void* d_out, int out_size, void* d_ws, size_t ws_size,
                              hipStream_t stream) {
  const float* x = (const float*)d_in[0];
  const float* bvq = (const float*)d_in[1];
  const float* bvk = (const float*)d_in[2];
  const float* bvv = (const float*)d_in[3];
  float* out = (float*)d_out;

  const size_t QB_SZ = (size_t)B_SZ * T_SZ * D_SZ;  // 8 MB (i8)
  const size_t NEED = QB_SZ * 2 + QB_SZ * 2;        // Qb + Kb + Vt(bf16) = 32 MB

  if (ws_size >= NEED) {
    char* Qb = (char*)d_ws;
    char* Kb = Qb + QB_SZ;
    ushort* Vt = (ushort*)(Kb + QB_SZ);
    hipLaunchKernelGGL(prep_kernel, dim3(B_SZ * 32 * 16), dim3(256), 0, stream,
                       x, bvq, bvk, bvv, Qb, Kb, Vt);
    hipLaunchKernelGGL(attn_main, dim3(B_SZ * 32 * 4), dim3(NTH), 0, stream,
                       Qb, Kb, Vt, out);
  } else {
    hipLaunchKernelGGL(hdc_attn_fallback, dim3(B_SZ * 64), dim3(NTH), 0, stream,
                       x, bvq, bvk, bvv, out);
  }
}

// Round 4
// 88.028 us; speedup vs baseline: 4.5178x; 4.5178x over previous
//
#include <hip/hip_runtime.h>
#include <hip/hip_bf16.h>
#include <stdint.h>

#define B_SZ 4
#define T_SZ 2048
#define D_SZ 1024

constexpr int NTH = 512;

typedef short bf16x8 __attribute__((ext_vector_type(8)));
typedef float f32x4 __attribute__((ext_vector_type(4)));
typedef int i32x4 __attribute__((ext_vector_type(4)));
typedef unsigned short ushort8 __attribute__((ext_vector_type(8)));

__device__ __forceinline__ uint32_t sbf(uint32_t xu, uint32_t su) {
  return 0x3F80u | (((xu ^ su) >> 16) & 0x8000u);
}

__device__ __forceinline__ ushort f2bf(float f) {  // RNE f32->bf16
  uint32_t u = __float_as_uint(f);
  return (ushort)((u + 0x7FFFu + ((u >> 16) & 1u)) >> 16);
}

// async 16B global->LDS (linear dest = wave base + lane*16)
__device__ __forceinline__ void glds16(const void* g, void* l) {
  __builtin_amdgcn_global_load_lds(
      (const __attribute__((address_space(1))) void*)g,
      (__attribute__((address_space(3))) void*)l, 16, 0, 0);
}

// ============================ PREP KERNEL =============================
// Qb,Kb: int8 sign(x)*sign(bq/bk) in [B][T][D].  Vt: bf16 x*sign(bv) in [B][D][T].
__global__ __launch_bounds__(256) void prep_kernel(
    const float* __restrict__ x, const float* __restrict__ bvq,
    const float* __restrict__ bvk, const float* __restrict__ bvv,
    char* __restrict__ Qb, char* __restrict__ Kb, ushort* __restrict__ Vt) {
  __shared__ ushort vt[64][72];
  const int bid = blockIdx.x;
  const int dt = bid & 15;
  const int tt = (bid >> 4) & 31;
  const int b = bid >> 9;
  const int t0 = tt * 64, d0 = dt * 64;
  const int tid = threadIdx.x;

#pragma unroll
  for (int p = 0; p < 4; ++p) {
    const int row = p * 16 + (tid >> 4);
    const int c4 = tid & 15;
    const size_t idx = ((size_t)(b * T_SZ + t0 + row)) * D_SZ + d0 + c4 * 4;
    float4 v = *(const float4*)(x + idx);
    float4 q = *(const float4*)(bvq + d0 + c4 * 4);
    float4 k = *(const float4*)(bvk + d0 + c4 * 4);
    float4 s = *(const float4*)(bvv + d0 + c4 * 4);
    uint32_t xu[4] = {__float_as_uint(v.x), __float_as_uint(v.y),
                      __float_as_uint(v.z), __float_as_uint(v.w)};
    uint32_t qu[4] = {__float_as_uint(q.x), __float_as_uint(q.y),
                      __float_as_uint(q.z), __float_as_uint(q.w)};
    uint32_t ku[4] = {__float_as_uint(k.x), __float_as_uint(k.y),
                      __float_as_uint(k.z), __float_as_uint(k.w)};
    uint32_t su[4] = {__float_as_uint(s.x), __float_as_uint(s.y),
                      __float_as_uint(s.z), __float_as_uint(s.w)};
    uint32_t qw = 0, kw = 0;
#pragma unroll
    for (int j = 0; j < 4; ++j) {
      uint32_t qb = ((xu[j] ^ qu[j]) & 0x80000000u) ? 0xFFu : 0x01u;
      uint32_t kb = ((xu[j] ^ ku[j]) & 0x80000000u) ? 0xFFu : 0x01u;
      qw |= qb << (8 * j);
      kw |= kb << (8 * j);
      vt[row][c4 * 4 + j] = f2bf(__uint_as_float(xu[j] ^ (su[j] & 0x80000000u)));
    }
    *(uint32_t*)(Qb + idx) = qw;
    *(uint32_t*)(Kb + idx) = kw;
  }
  __syncthreads();
#pragma unroll
  for (int p = 0; p < 2; ++p) {
    const int dr = p * 32 + (tid >> 3);
    const int tc = tid & 7;
    ushort8 o;
#pragma unroll
    for (int j = 0; j < 8; ++j) o[j] = vt[tc * 8 + j][dr];
    *(ushort8*)(Vt + ((size_t)(b * D_SZ + d0 + dr)) * T_SZ + t0 + tc * 8) = o;
  }
}

// ============================ SCORE KERNEL ============================
// P[b][q][s] = sigmoid(0.125 * dot_i8(Q[q],K[s])), causal-masked on diagonal
// tiles. 64x64 tile per block (4 waves), K=1024 in 4 steps of BK=256.
// LDS rows 256B, chunk swizzle: low-3 chunk bits ^= row&7 (src + read side).
__global__ __launch_bounds__(256) void score_kernel(
    const char* __restrict__ Qb, const char* __restrict__ Kb,
    ushort* __restrict__ P) {
  __shared__ __align__(16) unsigned char Qs[64 * 256];
  __shared__ __align__(16) unsigned char Ks[64 * 256];
  const int st = blockIdx.x, qt = blockIdx.y, b = blockIdx.z;
  if (st > qt) return;
  const int tid = threadIdx.x;
  const int lane = tid & 63, w = tid >> 6;
  const int wr = w >> 1, wc = w & 1;
  const int l15 = lane & 15, l4 = lane >> 4;

  i32x4 sacc[2][2];
#pragma unroll
  for (int mf = 0; mf < 2; ++mf)
#pragma unroll
    for (int nf = 0; nf < 2; ++nf) sacc[mf][nf] = (i32x4){0, 0, 0, 0};

  const size_t qrow0 = ((size_t)(b * T_SZ + qt * 64)) * D_SZ;
  const size_t krow0 = ((size_t)(b * T_SZ + st * 64)) * D_SZ;

  for (int ks = 0; ks < 4; ++ks) {
    __syncthreads();
#pragma unroll
    for (int i = 0; i < 4; ++i) {
      const int f = tid + i * 256;
      const int row = f >> 4, c = f & 15;
      const int cs = (c & 8) | ((c & 7) ^ (row & 7));
      const size_t off = (size_t)row * D_SZ + ks * 256 + cs * 16;
      glds16(Qb + qrow0 + off, Qs + f * 16);
      glds16(Kb + krow0 + off, Ks + f * 16);
    }
    asm volatile("s_waitcnt vmcnt(0)" ::: "memory");
    __syncthreads();
#pragma unroll
    for (int kc = 0; kc < 4; ++kc) {
      i32x4 af[2], bfr[2];
#pragma unroll
      for (int mf = 0; mf < 2; ++mf) {
        const int row = wr * 32 + mf * 16 + l15;
        const int ch = kc * 4 + l4;
        const int chs = (ch & 8) | ((ch & 7) ^ (row & 7));
        af[mf] = *(const i32x4*)(Qs + row * 256 + chs * 16);
      }
#pragma unroll
      for (int nf = 0; nf < 2; ++nf) {
        const int row = wc * 32 + nf * 16 + l15;
        const int ch = kc * 4 + l4;
        const int chs = (ch & 8) | ((ch & 7) ^ (row & 7));
        bfr[nf] = *(const i32x4*)(Ks + row * 256 + chs * 16);
      }
#pragma unroll
      for (int mf = 0; mf < 2; ++mf)
#pragma unroll
        for (int nf = 0; nf < 2; ++nf)
          sacc[mf][nf] = __builtin_amdgcn_mfma_i32_16x16x64_i8(
              af[mf], bfr[nf], sacc[mf][nf], 0, 0, 0);
    }
  }

  // sigmoid + causal mask + write P tile
#pragma unroll
  for (int mf = 0; mf < 2; ++mf)
#pragma unroll
    for (int nf = 0; nf < 2; ++nf)
#pragma unroll
      for (int r = 0; r < 4; ++r) {
        const int q = wr * 32 + mf * 16 + l4 * 4 + r;
        const int s = wc * 32 + nf * 16 + l15;
        float p = 1.f / (1.f + __expf(-0.125f * (float)sacc[mf][nf][r]));
        if (st == qt && s > q) p = 0.f;
        P[((size_t)(b * T_SZ + qt * 64 + q)) * T_SZ + st * 64 + s] = f2bf(p);
      }
}

// ============================== PV KERNEL =============================
// out[b][q][d] = sum_s P[q][s] * Vt[d][s].  Block = (b, ds 128-col slice,
// tile-pair (pr, 31-pr)) -> exactly 33 K-steps per block. 8 waves, wave =
// 32q x 32d. LDS rows 128B, chunk swizzle: chunk ^= row&7.
__global__ __launch_bounds__(NTH) void pv_kernel(
    const ushort* __restrict__ P, const ushort* __restrict__ Vt,
    float* __restrict__ out) {
  __shared__ __align__(16) unsigned char Pl[64 * 128];   // 8 KB
  __shared__ __align__(16) unsigned char Vl[128 * 128];  // 16 KB
  const int bid = blockIdx.x;
  const int pr = bid & 15;
  const int ds = (bid >> 4) & 7;
  const int b = bid >> 7;
  const int tid = threadIdx.x;
  const int lane = tid & 63, w = tid >> 6;
  const int wr = w >> 2, dg = w & 3;
  const int l15 = lane & 15, l4 = lane >> 4;

  const char* Pb = (const char*)P;
  const char* Vb = (const char*)Vt;

  for (int half = 0; half < 2; ++half) {
    const int qt = half ? (31 - pr) : pr;
    f32x4 acc[2][2];
#pragma unroll
    for (int mf = 0; mf < 2; ++mf)
#pragma unroll
      for (int nf = 0; nf < 2; ++nf) acc[mf][nf] = (f32x4){0.f, 0.f, 0.f, 0.f};

    const size_t prow0 = ((size_t)(b * T_SZ + qt * 64)) * (T_SZ * 2);
    const size_t vrow0 = ((size_t)(b * D_SZ + ds * 128)) * (T_SZ * 2);

    for (int st = 0; st <= qt; ++st) {
      __syncthreads();
      {  // stage P tile: 512 chunks, 1/thread
        const int row = tid >> 3, c = tid & 7;
        const int cs = c ^ (row & 7);
        glds16(Pb + prow0 + (size_t)row * (T_SZ * 2) + st * 128 + cs * 16,
               Pl + tid * 16);
      }
#pragma unroll
      for (int i = 0; i < 2; ++i) {  // stage V tile: 1024 chunks, 2/thread
        const int f = tid + i * 512;
        const int row = f >> 3, c = f & 7;
        const int cs = c ^ (row & 7);
        glds16(Vb + vrow0 + (size_t)row * (T_SZ * 2) + st * 128 + cs * 16,
               Vl + f * 16);
      }
      asm volatile("s_waitcnt vmcnt(0)" ::: "memory");
      __syncthreads();
#pragma unroll
      for (int kk = 0; kk < 2; ++kk) {
        bf16x8 pa[2], vb[2];
#pragma unroll
        for (int mf = 0; mf < 2; ++mf) {
          const int row = wr * 32 + mf * 16 + l15;
          const int ch = (kk * 4 + l4) ^ (row & 7);
          pa[mf] = *(const bf16x8*)(Pl + row * 128 + ch * 16);
        }
#pragma unroll
        for (int nf = 0; nf < 2; ++nf) {
          const int row = dg * 32 + nf * 16 + l15;
          const int ch = (kk * 4 + l4) ^ (row & 7);
          vb[nf] = *(const bf16x8*)(Vl + row * 128 + ch * 16);
        }
#pragma unroll
        for (int mf = 0; mf < 2; ++mf)
#pragma unroll
          for (int nf = 0; nf < 2; ++nf)
            acc[mf][nf] = __builtin_amdgcn_mfma_f32_16x16x32_bf16(
                pa[mf], vb[nf], acc[mf][nf], 0, 0, 0);
      }
    }

    float* ob = out + ((size_t)(b * T_SZ + qt * 64 + wr * 32)) * D_SZ +
                ds * 128 + dg * 32;
#pragma unroll
    for (int mf = 0; mf < 2; ++mf)
#pragma unroll
      for (int nf = 0; nf < 2; ++nf)
#pragma unroll
        for (int r = 0; r < 4; ++r)
          ob[(size_t)(mf * 16 + l4 * 4 + r) * D_SZ + nf * 16 + l15] =
              acc[mf][nf][r];
  }
}

// =================== MID FALLBACK (R2 attn_main, 32MB ws) =============
__global__ __launch_bounds__(NTH, 4) void attn_main(
    const char* __restrict__ Qb, const char* __restrict__ Kb,
    const ushort* __restrict__ Vt, float* __restrict__ out) {
  __shared__ __align__(16) unsigned char Qs[32][1040];
  __shared__ __align__(16) ushort Ps[32][72];
  const int tid = threadIdx.x;
  const int lane = tid & 63;
  const int w = tid >> 6;
  const int rg = w >> 2, cg = w & 3;
  const int l15 = lane & 15, l4 = lane >> 4;
  const int bid = blockIdx.x;
  const int half = bid & 1;
  const int ti = (bid >> 1) & 63;
  const int b = bid >> 7;
  const int t0 = ti * 32;
  {
    const int row = tid >> 4;
    const int c = (tid & 15) * 64;
    const uint4* src = (const uint4*)(Qb + ((size_t)(b * T_SZ + t0 + row)) * D_SZ + c);
    uint4 a0 = src[0], a1 = src[1], a2 = src[2], a3 = src[3];
    *(uint4*)&Qs[row][c] = a0;
    *(uint4*)&Qs[row][c + 16] = a1;
    *(uint4*)&Qs[row][c + 32] = a2;
    *(uint4*)&Qs[row][c + 48] = a3;
  }
  __syncthreads();
  const int nt = (t0 + 32 + 63) / 64;
  const int s_beg = half ? (nt + 1) / 2 : 0;
  const int s_end = half ? nt : (nt + 1) / 2;
  f32x4 acc[16];
#pragma unroll
  for (int f = 0; f < 16; ++f) acc[f] = (f32x4){0.f, 0.f, 0.f, 0.f};
  const unsigned char* qrow = &Qs[rg * 16 + l15][l4 * 16];
  for (int st = s_beg; st < s_end; ++st) {
    const int s0 = st * 64;
    i32x4 sacc = (i32x4){0, 0, 0, 0};
    const char* kbase = Kb + ((size_t)(b * T_SZ + s0 + cg * 16 + l15)) * D_SZ + l4 * 16;
#pragma unroll
    for (int kc = 0; kc < 16; ++kc) {
      i32x4 a = *(const i32x4*)(qrow + kc * 64);
      i32x4 kf = *(const i32x4*)(kbase + kc * 64);
      sacc = __builtin_amdgcn_mfma_i32_16x16x64_i8(a, kf, sacc, 0, 0, 0);
    }
    __syncthreads();
    {
      const int scol = cg * 16 + l15;
      const int sg = s0 + scol;
#pragma unroll
      for (int r = 0; r < 4; ++r) {
        const int m = rg * 16 + l4 * 4 + r;
        float p = 0.f;
        if (sg <= t0 + m) p = 1.f / (1.f + __expf(-0.125f * (float)sacc[r]));
        Ps[m][scol] = f2bf(p);
      }
    }
    __syncthreads();
    const ushort* vtb = Vt + ((size_t)(b * D_SZ + cg * 256)) * T_SZ + s0;
#pragma unroll
    for (int kk = 0; kk < 2; ++kk) {
      bf16x8 pa = *(const bf16x8*)&Ps[rg * 16 + l15][kk * 32 + l4 * 8];
      const ushort* vks = vtb + kk * 32 + l4 * 8;
#pragma unroll
      for (int f = 0; f < 16; ++f) {
        bf16x8 vb = *(const bf16x8*)(vks + (size_t)(f * 16 + l15) * T_SZ);
        acc[f] = __builtin_amdgcn_mfma_f32_16x16x32_bf16(pa, vb, acc[f], 0, 0, 0);
      }
    }
  }
  float* orow = out + ((size_t)(b * T_SZ + t0)) * D_SZ;
#pragma unroll
  for (int f = 0; f < 16; ++f) {
    const int n = cg * 256 + f * 16 + l15;
#pragma unroll
    for (int r = 0; r < 4; ++r) {
      const int m = rg * 16 + l4 * 4 + r;
      atomicAdd(orow + (size_t)m * D_SZ + n, acc[f][r]);
    }
  }
}

// ===================== BASE FALLBACK (no ws needed) ===================
__global__ __launch_bounds__(NTH) void hdc_attn_fallback(
    const float* __restrict__ x, const float* __restrict__ bvq,
    const float* __restrict__ bvk, const float* __restrict__ bvv,
    float* __restrict__ out) {
  __shared__ ushort Qs[32][1032];
  __shared__ ushort Ks[64][72];
  __shared__ ushort Ps[32][72];
  const int tid = threadIdx.x;
  const int lane = tid & 63;
  const int w = tid >> 6;
  const int rg = w >> 2, cg = w & 3;
  const int l15 = lane & 15, l4 = lane >> 4;
  const int b = blockIdx.x >> 6;
  const int ti = blockIdx.x & 63;
  const int t0 = ti * 32;
  {
    const float4* xr = (const float4*)(x + ((size_t)b * T_SZ + t0) * D_SZ);
    const float4* bq4 = (const float4*)bvq;
#pragma unroll
    for (int i = 0; i < 16; ++i) {
      int flat4 = tid + i * NTH;
      int row = flat4 >> 8, c4 = flat4 & 255;
      float4 v = xr[row * 256 + c4];
      float4 q = bq4[c4];
      uint32_t q0 = sbf(__float_as_uint(v.x), __float_as_uint(q.x));
      uint32_t q1 = sbf(__float_as_uint(v.y), __float_as_uint(q.y));
      uint32_t q2 = sbf(__float_as_uint(v.z), __float_as_uint(q.z));
      uint32_t q3 = sbf(__float_as_uint(v.w), __float_as_uint(q.w));
      *(uint2*)&Qs[row][c4 * 4] = make_uint2(q0 | (q1 << 16), q2 | (q3 << 16));
    }
  }
  uint32_t vsign[16];
#pragma unroll
  for (int f = 0; f < 16; ++f)
    vsign[f] = __float_as_uint(bvv[cg * 256 + f * 16 + l15]) & 0x80000000u;
  f32x4 acc[16];
#pragma unroll
  for (int f = 0; f < 16; ++f) acc[f] = (f32x4){0.f, 0.f, 0.f, 0.f};
  const int nt = (t0 + 32 + 63) / 64;
  for (int st = 0; st < nt; ++st) {
    const int s0 = st * 64;
    f32x4 sacc = (f32x4){0.f, 0.f, 0.f, 0.f};
    for (int dc = 0; dc < D_SZ / 64; ++dc) {
      __syncthreads();
      {
        const int s = tid >> 3;
        const int c8 = (tid & 7) * 8;
        const float* xk = x + ((size_t)b * T_SZ + s0 + s) * D_SZ + dc * 64 + c8;
        const float* bk = bvk + dc * 64 + c8;
        float4 v0 = *(const float4*)xk;
        float4 v1 = *(const float4*)(xk + 4);
        float4 k0 = *(const float4*)bk;
        float4 k1 = *(const float4*)(bk + 4);
        uint32_t w0 = sbf(__float_as_uint(v0.x), __float_as_uint(k0.x)) |
                      (sbf(__float_as_uint(v0.y), __float_as_uint(k0.y)) << 16);
        uint32_t w1 = sbf(__float_as_uint(v0.z), __float_as_uint(k0.z)) |
                      (sbf(__float_as_uint(v0.w), __float_as_uint(k0.w)) << 16);
        uint32_t w2 = sbf(__float_as_uint(v1.x), __float_as_uint(k1.x)) |
                      (sbf(__float_as_uint(v1.y), __float_as_uint(k1.y)) << 16);
        uint32_t w3 = sbf(__float_as_uint(v1.z), __float_as_uint(k1.z)) |
                      (sbf(__float_as_uint(v1.w), __float_as_uint(k1.w)) << 16);
        *(uint4*)&Ks[s][c8] = make_uint4(w0, w1, w2, w3);
      }
      __syncthreads();
#pragma unroll
      for (int h = 0; h < 2; ++h) {
        bf16x8 a = *(const bf16x8*)&Qs[rg * 16 + l15][dc * 64 + h * 32 + l4 * 8];
        bf16x8 kb = *(const bf16x8*)&Ks[cg * 16 + l15][h * 32 + l4 * 8];
        sacc = __builtin_amdgcn_mfma_f32_16x16x32_bf16(a, kb, sacc, 0, 0, 0);
      }
    }
    {
      const int scol = cg * 16 + l15;
      const int sg = s0 + scol;
#pragma unroll
      for (int r = 0; r < 4; ++r) {
        const int m = rg * 16 + l4 * 4 + r;
        float p = 0.f;
        if (sg <= t0 + m) p = 1.f / (1.f + __expf(-0.125f * sacc[r]));
        Ps[m][scol] = (ushort)(__float_as_uint(p) >> 16);
      }
    }
    __syncthreads();
    const float* xv = x + ((size_t)b * T_SZ + s0) * D_SZ;
#pragma unroll
    for (int kk = 0; kk < 2; ++kk) {
      bf16x8 pa = *(const bf16x8*)&Ps[rg * 16 + l15][kk * 32 + l4 * 8];
      const float* xvs = xv + (size_t)(kk * 32 + l4 * 8) * D_SZ;
#pragma unroll
      for (int f = 0; f < 16; ++f) {
        const int n = cg * 256 + f * 16 + l15;
        const float* xn = xvs + n;
        bf16x8 vb;
#pragma unroll
        for (int i = 0; i < 8; ++i) {
          uint32_t u = __float_as_uint(xn[(size_t)i * D_SZ]) ^ vsign[f];
          vb[i] = (short)(u >> 16);
        }
        acc[f] = __builtin_amdgcn_mfma_f32_16x16x32_bf16(pa, vb, acc[f], 0, 0, 0);
      }
    }
  }
  float* orow = out + ((size_t)b * T_SZ + t0) * D_SZ;
#pragma unroll
  for (int f = 0; f < 16; ++f) {
    const int n = cg * 256 + f * 16 + l15;
#pragma unroll
    for (int r = 0; r < 4; ++r) {
      const int m = rg * 16 + l4 * 4 + r;
      orow[(size_t)m * D_SZ + n] = acc[f][r];
    }
  }
}

extern "C" void kernel_launch(void* const* d_in, const int* in_sizes, int n_in,
                              void* d_out, int out_size, void* d_ws, size_t ws_size,
                              hipStream_t stream) {
  const float* x = (const float*)d_in[0];
  const float* bvq = (const float*)d_in[1];
  const float* bvk = (const float*)d_in[2];
  const float* bvv = (const float*)d_in[3];
  float* out = (float*)d_out;

  const size_t QB_SZ = (size_t)B_SZ * T_SZ * D_SZ;   // 8 MB (i8)
  const size_t VT_SZ = QB_SZ * 2;                    // 16 MB (bf16)
  const size_t P_SZ = (size_t)B_SZ * T_SZ * T_SZ * 2;  // 32 MB (bf16)
  const size_t NEED_MID = QB_SZ * 2 + VT_SZ;           // 32 MB
  const size_t NEED_FULL = NEED_MID + P_SZ;            // 64 MB

  if (ws_size >= NEED_MID) {
    char* Qb = (char*)d_ws;
    char* Kb = Qb + QB_SZ;
    ushort* Vt = (ushort*)(Kb + QB_SZ);
    hipLaunchKernelGGL(prep_kernel, dim3(B_SZ * 32 * 16), dim3(256), 0, stream,
                       x, bvq, bvk, bvv, Qb, Kb, Vt);
    if (ws_size >= NEED_FULL) {
      ushort* P = (ushort*)((char*)d_ws + NEED_MID);
      hipLaunchKernelGGL(score_kernel, dim3(32, 32, B_SZ), dim3(256), 0, stream,
                         Qb, Kb, P);
      hipLaunchKernelGGL(pv_kernel, dim3(16 * 8 * B_SZ), dim3(NTH), 0, stream,
                         P, Vt, out);
    } else {
      hipMemsetAsync(out, 0, (size_t)out_size * sizeof(float), stream);
      hipLaunchKernelGGL(attn_main, dim3(B_SZ * 64 * 2), dim3(NTH), 0, stream,
                         Qb, Kb, Vt, out);
    }
  } else {
    hipLaunchKernelGGL(hdc_attn_fallback, dim3(B_SZ * 64), dim3(NTH), 0, stream,
                       x, bvq, bvk, bvv, out);
  }
}

// Round 5
// 86.865 us; speedup vs baseline: 4.5783x; 1.0134x over previous
//
#include <hip/hip_runtime.h>
#include <hip/hip_bf16.h>
#include <stdint.h>
#include <math.h>

#define B_SZ 4
#define T_SZ 2048
#define D_SZ 1024

constexpr int NTH = 512;

typedef short bf16x8 __attribute__((ext_vector_type(8)));
typedef float f32x4 __attribute__((ext_vector_type(4)));
typedef int i32x4 __attribute__((ext_vector_type(4)));
typedef unsigned short ushort8 __attribute__((ext_vector_type(8)));

__device__ __forceinline__ uint32_t sbf(uint32_t xu, uint32_t su) {
  return 0x3F80u | (((xu ^ su) >> 16) & 0x8000u);
}

__device__ __forceinline__ ushort f2bf(float f) {  // RNE f32->bf16
  uint32_t u = __float_as_uint(f);
  return (ushort)((u + 0x7FFFu + ((u >> 16) & 1u)) >> 16);
}

// async 16B global->LDS (dest = wave-uniform base + lane*16 pattern)
__device__ __forceinline__ void glds16(const void* g, void* l) {
  __builtin_amdgcn_global_load_lds(
      (const __attribute__((address_space(1))) void*)g,
      (__attribute__((address_space(3))) void*)l, 16, 0, 0);
}

// ============================ PREP KERNEL =============================
// Qb,Kb: int8 sign(x)*sign(bq/bk) in [B][T][D].  Vt: bf16 x*sign(bv) in [B][D][T].
__global__ __launch_bounds__(256) void prep_kernel(
    const float* __restrict__ x, const float* __restrict__ bvq,
    const float* __restrict__ bvk, const float* __restrict__ bvv,
    char* __restrict__ Qb, char* __restrict__ Kb, ushort* __restrict__ Vt) {
  __shared__ ushort vt[64][72];
  const int bid = blockIdx.x;
  const int dt = bid & 15;
  const int tt = (bid >> 4) & 31;
  const int b = bid >> 9;
  const int t0 = tt * 64, d0 = dt * 64;
  const int tid = threadIdx.x;

#pragma unroll
  for (int p = 0; p < 4; ++p) {
    const int row = p * 16 + (tid >> 4);
    const int c4 = tid & 15;
    const size_t idx = ((size_t)(b * T_SZ + t0 + row)) * D_SZ + d0 + c4 * 4;
    float4 v = *(const float4*)(x + idx);
    float4 q = *(const float4*)(bvq + d0 + c4 * 4);
    float4 k = *(const float4*)(bvk + d0 + c4 * 4);
    float4 s = *(const float4*)(bvv + d0 + c4 * 4);
    uint32_t xu[4] = {__float_as_uint(v.x), __float_as_uint(v.y),
                      __float_as_uint(v.z), __float_as_uint(v.w)};
    uint32_t qu[4] = {__float_as_uint(q.x), __float_as_uint(q.y),
                      __float_as_uint(q.z), __float_as_uint(q.w)};
    uint32_t ku[4] = {__float_as_uint(k.x), __float_as_uint(k.y),
                      __float_as_uint(k.z), __float_as_uint(k.w)};
    uint32_t su[4] = {__float_as_uint(s.x), __float_as_uint(s.y),
                      __float_as_uint(s.z), __float_as_uint(s.w)};
    uint32_t qw = 0, kw = 0;
#pragma unroll
    for (int j = 0; j < 4; ++j) {
      uint32_t qb = ((xu[j] ^ qu[j]) & 0x80000000u) ? 0xFFu : 0x01u;
      uint32_t kb = ((xu[j] ^ ku[j]) & 0x80000000u) ? 0xFFu : 0x01u;
      qw |= qb << (8 * j);
      kw |= kb << (8 * j);
      vt[row][c4 * 4 + j] = f2bf(__uint_as_float(xu[j] ^ (su[j] & 0x80000000u)));
    }
    *(uint32_t*)(Qb + idx) = qw;
    *(uint32_t*)(Kb + idx) = kw;
  }
  __syncthreads();
#pragma unroll
  for (int p = 0; p < 2; ++p) {
    const int dr = p * 32 + (tid >> 3);
    const int tc = tid & 7;
    ushort8 o;
#pragma unroll
    for (int j = 0; j < 8; ++j) o[j] = vt[tc * 8 + j][dr];
    *(ushort8*)(Vt + ((size_t)(b * D_SZ + d0 + dr)) * T_SZ + t0 + tc * 8) = o;
  }
}

// ============================ SCORE KERNEL ============================
// 128x128 tile per block, 8 waves (wave = 32q x 64s), BK=128, double-buffered
// LDS with raw barriers + prefetch. Triangular grid: blockIdx.x in [0,136).
__global__ __launch_bounds__(NTH) void score_kernel(
    const char* __restrict__ Qb, const char* __restrict__ Kb,
    ushort* __restrict__ P) {
  __shared__ __align__(16) unsigned char Qs[2][128 * 128];  // 32 KB
  __shared__ __align__(16) unsigned char Ks[2][128 * 128];  // 32 KB

  const int j = blockIdx.x;
  const int b = blockIdx.y;
  int qt = (int)((sqrtf(8.f * (float)j + 1.f) - 1.f) * 0.5f);
  while ((qt + 1) * (qt + 2) / 2 <= j) ++qt;
  while (qt * (qt + 1) / 2 > j) --qt;
  const int st = j - qt * (qt + 1) / 2;

  const int tid = threadIdx.x;
  const int lane = tid & 63, w = tid >> 6;
  const int wr = w >> 1, wc = w & 1;
  const int l15 = lane & 15, l4 = lane >> 4;

  const size_t qrow0 = ((size_t)(b * T_SZ + qt * 128)) * D_SZ;
  const size_t krow0 = ((size_t)(b * T_SZ + st * 128)) * D_SZ;

  i32x4 sacc[2][4];
#pragma unroll
  for (int mf = 0; mf < 2; ++mf)
#pragma unroll
    for (int nf = 0; nf < 4; ++nf) sacc[mf][nf] = (i32x4){0, 0, 0, 0};

  // stage K-chunk ks (128 i8 cols) of Q and K tiles into buf (4 glds/thread)
  auto STAGE = [&](int buf, int ks) {
#pragma unroll
    for (int i = 0; i < 4; ++i) {
      const int isK = i >> 1;
      const int fi = tid + (i & 1) * 512;  // 0..1023 chunk within tile
      const int row = fi >> 3, c = fi & 7;
      const int cs = c ^ (row & 7);
      const char* src = (isK ? Kb + krow0 : Qb + qrow0) +
                        (size_t)row * D_SZ + ks * 128 + cs * 16;
      unsigned char* dst = (isK ? Ks[buf] : Qs[buf]) + fi * 16;
      glds16(src, dst);
    }
  };

  STAGE(0, 0);
  for (int ks = 0; ks < 8; ++ks) {
    asm volatile("s_waitcnt vmcnt(0)" ::: "memory");
    __builtin_amdgcn_s_barrier();
    if (ks + 1 < 8) STAGE((ks + 1) & 1, ks + 1);
    const int buf = ks & 1;
#pragma unroll
    for (int kc = 0; kc < 2; ++kc) {
      i32x4 af[2], bfr[4];
#pragma unroll
      for (int mf = 0; mf < 2; ++mf) {
        const int row = wr * 32 + mf * 16 + l15;
        const int ch = (kc * 4 + l4) ^ (row & 7);
        af[mf] = *(const i32x4*)(Qs[buf] + row * 128 + ch * 16);
      }
#pragma unroll
      for (int nf = 0; nf < 4; ++nf) {
        const int row = wc * 64 + nf * 16 + l15;
        const int ch = (kc * 4 + l4) ^ (row & 7);
        bfr[nf] = *(const i32x4*)(Ks[buf] + row * 128 + ch * 16);
      }
#pragma unroll
      for (int mf = 0; mf < 2; ++mf)
#pragma unroll
        for (int nf = 0; nf < 4; ++nf)
          sacc[mf][nf] = __builtin_amdgcn_mfma_i32_16x16x64_i8(
              af[mf], bfr[nf], sacc[mf][nf], 0, 0, 0);
    }
    asm volatile("s_waitcnt lgkmcnt(0)" ::: "memory");
  }

  // sigmoid + causal mask + write
#pragma unroll
  for (int mf = 0; mf < 2; ++mf)
#pragma unroll
    for (int nf = 0; nf < 4; ++nf)
#pragma unroll
      for (int r = 0; r < 4; ++r) {
        const int qg = qt * 128 + wr * 32 + mf * 16 + l4 * 4 + r;
        const int sg = st * 128 + wc * 64 + nf * 16 + l15;
        float p = 1.f / (1.f + __expf(-0.125f * (float)sacc[mf][nf][r]));
        if (sg > qg) p = 0.f;
        P[((size_t)(b * T_SZ + qg)) * T_SZ + sg] = f2bf(p);
      }
}

// ============================== PV KERNEL =============================
// out[b][q][d] = sum_s P[q][s] * Vt[d][s].  Block = (b, ds 128-col slice,
// tile-pair (pr, 31-pr)). Triple-buffered LDS, prefetch distance 2, counted
// vmcnt (never 0 mid-loop), one raw barrier per K-step.
__global__ __launch_bounds__(NTH) void pv_kernel(
    const ushort* __restrict__ P, const ushort* __restrict__ Vt,
    float* __restrict__ out) {
  __shared__ __align__(16) unsigned char Pl[3][64 * 128];   // 24 KB
  __shared__ __align__(16) unsigned char Vl[3][128 * 128];  // 48 KB
  const int bid = blockIdx.x;
  const int pr = bid & 15;
  const int ds = (bid >> 4) & 7;
  const int b = bid >> 7;
  const int tid = threadIdx.x;
  const int lane = tid & 63, w = tid >> 6;
  const int wr = w >> 2, dg = w & 3;
  const int l15 = lane & 15, l4 = lane >> 4;

  const char* Pb = (const char*)P;
  const char* Vb = (const char*)Vt;

  for (int half = 0; half < 2; ++half) {
    const int qt = half ? (31 - pr) : pr;
    const int nst = qt + 1;
    const size_t prow0 = ((size_t)(b * T_SZ + qt * 64)) * (T_SZ * 2);
    const size_t vrow0 = ((size_t)(b * D_SZ + ds * 128)) * (T_SZ * 2);

    // stage s-tile stt (64 s-cols): 1 P chunk + 2 V chunks per thread
    auto STAGE = [&](int buf, int stt) {
      {
        const int row = tid >> 3, c = tid & 7;
        const int cs = c ^ (row & 7);
        glds16(Pb + prow0 + (size_t)row * (T_SZ * 2) + stt * 128 + cs * 16,
               Pl[buf] + tid * 16);
      }
#pragma unroll
      for (int i = 0; i < 2; ++i) {
        const int f = tid + i * 512;
        const int row = f >> 3, c = f & 7;
        const int cs = c ^ (row & 7);
        glds16(Vb + vrow0 + (size_t)row * (T_SZ * 2) + stt * 128 + cs * 16,
               Vl[buf] + f * 16);
      }
    };

    if (half) __builtin_amdgcn_s_barrier();  // all waves done reading bufs

    f32x4 acc[2][2];
#pragma unroll
    for (int mf = 0; mf < 2; ++mf)
#pragma unroll
      for (int nf = 0; nf < 2; ++nf) acc[mf][nf] = (f32x4){0.f, 0.f, 0.f, 0.f};

    STAGE(0, 0);
    if (nst > 1) STAGE(1, 1);

    for (int t = 0; t < nst; ++t) {
      if (t + 1 < nst)
        asm volatile("s_waitcnt vmcnt(3)" ::: "memory");  // tile t landed
      else
        asm volatile("s_waitcnt vmcnt(0)" ::: "memory");
      __builtin_amdgcn_s_barrier();
      if (t + 2 < nst) STAGE((t + 2) % 3, t + 2);
      const int buf = t % 3;
#pragma unroll
      for (int kk = 0; kk < 2; ++kk) {
        bf16x8 pa[2], vb[2];
#pragma unroll
        for (int mf = 0; mf < 2; ++mf) {
          const int row = wr * 32 + mf * 16 + l15;
          const int ch = (kk * 4 + l4) ^ (row & 7);
          pa[mf] = *(const bf16x8*)(Pl[buf] + row * 128 + ch * 16);
        }
#pragma unroll
        for (int nf = 0; nf < 2; ++nf) {
          const int row = dg * 32 + nf * 16 + l15;
          const int ch = (kk * 4 + l4) ^ (row & 7);
          vb[nf] = *(const bf16x8*)(Vl[buf] + row * 128 + ch * 16);
        }
#pragma unroll
        for (int mf = 0; mf < 2; ++mf)
#pragma unroll
          for (int nf = 0; nf < 2; ++nf)
            acc[mf][nf] = __builtin_amdgcn_mfma_f32_16x16x32_bf16(
                pa[mf], vb[nf], acc[mf][nf], 0, 0, 0);
      }
      asm volatile("s_waitcnt lgkmcnt(0)" ::: "memory");  // reads drained
    }

    float* ob = out + ((size_t)(b * T_SZ + qt * 64 + wr * 32)) * D_SZ +
                ds * 128 + dg * 32;
#pragma unroll
    for (int mf = 0; mf < 2; ++mf)
#pragma unroll
      for (int nf = 0; nf < 2; ++nf)
#pragma unroll
        for (int r = 0; r < 4; ++r)
          ob[(size_t)(mf * 16 + l4 * 4 + r) * D_SZ + nf * 16 + l15] =
              acc[mf][nf][r];
  }
}

// =================== MID FALLBACK (R2 attn_main, 32MB ws) =============
__global__ __launch_bounds__(NTH, 4) void attn_main(
    const char* __restrict__ Qb, const char* __restrict__ Kb,
    const ushort* __restrict__ Vt, float* __restrict__ out) {
  __shared__ __align__(16) unsigned char Qs[32][1040];
  __shared__ __align__(16) ushort Ps[32][72];
  const int tid = threadIdx.x;
  const int lane = tid & 63;
  const int w = tid >> 6;
  const int rg = w >> 2, cg = w & 3;
  const int l15 = lane & 15, l4 = lane >> 4;
  const int bid = blockIdx.x;
  const int half = bid & 1;
  const int ti = (bid >> 1) & 63;
  const int b = bid >> 7;
  const int t0 = ti * 32;
  {
    const int row = tid >> 4;
    const int c = (tid & 15) * 64;
    const uint4* src = (const uint4*)(Qb + ((size_t)(b * T_SZ + t0 + row)) * D_SZ + c);
    uint4 a0 = src[0], a1 = src[1], a2 = src[2], a3 = src[3];
    *(uint4*)&Qs[row][c] = a0;
    *(uint4*)&Qs[row][c + 16] = a1;
    *(uint4*)&Qs[row][c + 32] = a2;
    *(uint4*)&Qs[row][c + 48] = a3;
  }
  __syncthreads();
  const int nt = (t0 + 32 + 63) / 64;
  const int s_beg = half ? (nt + 1) / 2 : 0;
  const int s_end = half ? nt : (nt + 1) / 2;
  f32x4 acc[16];
#pragma unroll
  for (int f = 0; f < 16; ++f) acc[f] = (f32x4){0.f, 0.f, 0.f, 0.f};
  const unsigned char* qrow = &Qs[rg * 16 + l15][l4 * 16];
  for (int st = s_beg; st < s_end; ++st) {
    const int s0 = st * 64;
    i32x4 sacc = (i32x4){0, 0, 0, 0};
    const char* kbase = Kb + ((size_t)(b * T_SZ + s0 + cg * 16 + l15)) * D_SZ + l4 * 16;
#pragma unroll
    for (int kc = 0; kc < 16; ++kc) {
      i32x4 a = *(const i32x4*)(qrow + kc * 64);
      i32x4 kf = *(const i32x4*)(kbase + kc * 64);
      sacc = __builtin_amdgcn_mfma_i32_16x16x64_i8(a, kf, sacc, 0, 0, 0);
    }
    __syncthreads();
    {
      const int scol = cg * 16 + l15;
      const int sg = s0 + scol;
#pragma unroll
      for (int r = 0; r < 4; ++r) {
        const int m = rg * 16 + l4 * 4 + r;
        float p = 0.f;
        if (sg <= t0 + m) p = 1.f / (1.f + __expf(-0.125f * (float)sacc[r]));
        Ps[m][scol] = f2bf(p);
      }
    }
    __syncthreads();
    const ushort* vtb = Vt + ((size_t)(b * D_SZ + cg * 256)) * T_SZ + s0;
#pragma unroll
    for (int kk = 0; kk < 2; ++kk) {
      bf16x8 pa = *(const bf16x8*)&Ps[rg * 16 + l15][kk * 32 + l4 * 8];
      const ushort* vks = vtb + kk * 32 + l4 * 8;
#pragma unroll
      for (int f = 0; f < 16; ++f) {
        bf16x8 vb = *(const bf16x8*)(vks + (size_t)(f * 16 + l15) * T_SZ);
        acc[f] = __builtin_amdgcn_mfma_f32_16x16x32_bf16(pa, vb, acc[f], 0, 0, 0);
      }
    }
  }
  float* orow = out + ((size_t)(b * T_SZ + t0)) * D_SZ;
#pragma unroll
  for (int f = 0; f < 16; ++f) {
    const int n = cg * 256 + f * 16 + l15;
#pragma unroll
    for (int r = 0; r < 4; ++r) {
      const int m = rg * 16 + l4 * 4 + r;
      atomicAdd(orow + (size_t)m * D_SZ + n, acc[f][r]);
    }
  }
}

// ===================== BASE FALLBACK (no ws needed) ===================
__global__ __launch_bounds__(NTH) void hdc_attn_fallback(
    const float* __restrict__ x, const float* __restrict__ bvq,
    const float* __restrict__ bvk, const float* __restrict__ bvv,
    float* __restrict__ out) {
  __shared__ ushort Qs[32][1032];
  __shared__ ushort Ks[64][72];
  __shared__ ushort Ps[32][72];
  const int tid = threadIdx.x;
  const int lane = tid & 63;
  const int w = tid >> 6;
  const int rg = w >> 2, cg = w & 3;
  const int l15 = lane & 15, l4 = lane >> 4;
  const int b = blockIdx.x >> 6;
  const int ti = blockIdx.x & 63;
  const int t0 = ti * 32;
  {
    const float4* xr = (const float4*)(x + ((size_t)b * T_SZ + t0) * D_SZ);
    const float4* bq4 = (const float4*)bvq;
#pragma unroll
    for (int i = 0; i < 16; ++i) {
      int flat4 = tid + i * NTH;
      int row = flat4 >> 8, c4 = flat4 & 255;
      float4 v = xr[row * 256 + c4];
      float4 q = bq4[c4];
      uint32_t q0 = sbf(__float_as_uint(v.x), __float_as_uint(q.x));
      uint32_t q1 = sbf(__float_as_uint(v.y), __float_as_uint(q.y));
      uint32_t q2 = sbf(__float_as_uint(v.z), __float_as_uint(q.z));
      uint32_t q3 = sbf(__float_as_uint(v.w), __float_as_uint(q.w));
      *(uint2*)&Qs[row][c4 * 4] = make_uint2(q0 | (q1 << 16), q2 | (q3 << 16));
    }
  }
  uint32_t vsign[16];
#pragma unroll
  for (int f = 0; f < 16; ++f)
    vsign[f] = __float_as_uint(bvv[cg * 256 + f * 16 + l15]) & 0x80000000u;
  f32x4 acc[16];
#pragma unroll
  for (int f = 0; f < 16; ++f) acc[f] = (f32x4){0.f, 0.f, 0.f, 0.f};
  const int nt = (t0 + 32 + 63) / 64;
  for (int st = 0; st < nt; ++st) {
    const int s0 = st * 64;
    f32x4 sacc = (f32x4){0.f, 0.f, 0.f, 0.f};
    for (int dc = 0; dc < D_SZ / 64; ++dc) {
      __syncthreads();
      {
        const int s = tid >> 3;
        const int c8 = (tid & 7) * 8;
        const float* xk = x + ((size_t)b * T_SZ + s0 + s) * D_SZ + dc * 64 + c8;
        const float* bk = bvk + dc * 64 + c8;
        float4 v0 = *(const float4*)xk;
        float4 v1 = *(const float4*)(xk + 4);
        float4 k0 = *(const float4*)bk;
        float4 k1 = *(const float4*)(bk + 4);
        uint32_t w0 = sbf(__float_as_uint(v0.x), __float_as_uint(k0.x)) |
                      (sbf(__float_as_uint(v0.y), __float_as_uint(k0.y)) << 16);
        uint32_t w1 = sbf(__float_as_uint(v0.z), __float_as_uint(k0.z)) |
                      (sbf(__float_as_uint(v0.w), __float_as_uint(k0.w)) << 16);
        uint32_t w2 = sbf(__float_as_uint(v1.x), __float_as_uint(k1.x)) |
                      (sbf(__float_as_uint(v1.y), __float_as_uint(k1.y)) << 16);
        uint32_t w3 = sbf(__float_as_uint(v1.z), __float_as_uint(k1.z)) |
                      (sbf(__float_as_uint(v1.w), __float_as_uint(k1.w)) << 16);
        *(uint4*)&Ks[s][c8] = make_uint4(w0, w1, w2, w3);
      }
      __syncthreads();
#pragma unroll
      for (int h = 0; h < 2; ++h) {
        bf16x8 a = *(const bf16x8*)&Qs[rg * 16 + l15][dc * 64 + h * 32 + l4 * 8];
        bf16x8 kb = *(const bf16x8*)&Ks[cg * 16 + l15][h * 32 + l4 * 8];
        sacc = __builtin_amdgcn_mfma_f32_16x16x32_bf16(a, kb, sacc, 0, 0, 0);
      }
    }
    {
      const int scol = cg * 16 + l15;
      const int sg = s0 + scol;
#pragma unroll
      for (int r = 0; r < 4; ++r) {
        const int m = rg * 16 + l4 * 4 + r;
        float p = 0.f;
        if (sg <= t0 + m) p = 1.f / (1.f + __expf(-0.125f * sacc[r]));
        Ps[m][scol] = (ushort)(__float_as_uint(p) >> 16);
      }
    }
    __syncthreads();
    const float* xv = x + ((size_t)b * T_SZ + s0) * D_SZ;
#pragma unroll
    for (int kk = 0; kk < 2; ++kk) {
      bf16x8 pa = *(const bf16x8*)&Ps[rg * 16 + l15][kk * 32 + l4 * 8];
      const float* xvs = xv + (size_t)(kk * 32 + l4 * 8) * D_SZ;
#pragma unroll
      for (int f = 0; f < 16; ++f) {
        const int n = cg * 256 + f * 16 + l15;
        const float* xn = xvs + n;
        bf16x8 vb;
#pragma unroll
        for (int i = 0; i < 8; ++i) {
          uint32_t u = __float_as_uint(xn[(size_t)i * D_SZ]) ^ vsign[f];
          vb[i] = (short)(u >> 16);
        }
        acc[f] = __builtin_amdgcn_mfma_f32_16x16x32_bf16(pa, vb, acc[f], 0, 0, 0);
      }
    }
  }
  float* orow = out + ((size_t)b * T_SZ + t0) * D_SZ;
#pragma unroll
  for (int f = 0; f < 16; ++f) {
    const int n = cg * 256 + f * 16 + l15;
#pragma unroll
    for (int r = 0; r < 4; ++r) {
      const int m = rg * 16 + l4 * 4 + r;
      orow[(size_t)m * D_SZ + n] = acc[f][r];
    }
  }
}

extern "C" void kernel_launch(void* const* d_in, const int* in_sizes, int n_in,
                              void* d_out, int out_size, void* d_ws, size_t ws_size,
                              hipStream_t stream) {
  const float* x = (const float*)d_in[0];
  const float* bvq = (const float*)d_in[1];
  const float* bvk = (const float*)d_in[2];
  const float* bvv = (const float*)d_in[3];
  float* out = (float*)d_out;

  const size_t QB_SZ = (size_t)B_SZ * T_SZ * D_SZ;     // 8 MB (i8)
  const size_t VT_SZ = QB_SZ * 2;                      // 16 MB (bf16)
  const size_t P_SZ = (size_t)B_SZ * T_SZ * T_SZ * 2;  // 32 MB (bf16)
  const size_t NEED_MID = QB_SZ * 2 + VT_SZ;           // 32 MB
  const size_t NEED_FULL = NEED_MID + P_SZ;            // 64 MB

  if (ws_size >= NEED_MID) {
    char* Qb = (char*)d_ws;
    char* Kb = Qb + QB_SZ;
    ushort* Vt = (ushort*)(Kb + QB_SZ);
    hipLaunchKernelGGL(prep_kernel, dim3(B_SZ * 32 * 16), dim3(256), 0, stream,
                       x, bvq, bvk, bvv, Qb, Kb, Vt);
    if (ws_size >= NEED_FULL) {
      ushort* P = (ushort*)((char*)d_ws + NEED_MID);
      hipLaunchKernelGGL(score_kernel, dim3(136, B_SZ), dim3(NTH), 0, stream,
                         Qb, Kb, P);
      hipLaunchKernelGGL(pv_kernel, dim3(16 * 8 * B_SZ), dim3(NTH), 0, stream,
                         P, Vt, out);
    } else {
      hipMemsetAsync(out, 0, (size_t)out_size * sizeof(float), stream);
      hipLaunchKernelGGL(attn_main, dim3(B_SZ * 64 * 2), dim3(NTH), 0, stream,
                         Qb, Kb, Vt, out);
    }
  } else {
    hipLaunchKernelGGL(hdc_attn_fallback, dim3(B_SZ * 64), dim3(NTH), 0, stream,
                       x, bvq, bvk, bvv, out);
  }
}

// Round 6
// 74.254 us; speedup vs baseline: 5.3558x; 1.1698x over previous
//
#include <hip/hip_runtime.h>
#include <hip/hip_bf16.h>
#include <stdint.h>
#include <math.h>

#define B_SZ 4
#define T_SZ 2048
#define D_SZ 1024

constexpr int NTH = 512;

typedef short bf16x8 __attribute__((ext_vector_type(8)));
typedef float f32x4 __attribute__((ext_vector_type(4)));
typedef int i32x4 __attribute__((ext_vector_type(4)));
typedef unsigned short ushort8 __attribute__((ext_vector_type(8)));

__device__ __forceinline__ uint32_t sbf(uint32_t xu, uint32_t su) {
  return 0x3F80u | (((xu ^ su) >> 16) & 0x8000u);
}

__device__ __forceinline__ ushort f2bf(float f) {  // RNE f32->bf16
  uint32_t u = __float_as_uint(f);
  return (ushort)((u + 0x7FFFu + ((u >> 16) & 1u)) >> 16);
}

// async 16B global->LDS (dest = wave-uniform base + lane*16 pattern)
__device__ __forceinline__ void glds16(const void* g, void* l) {
  __builtin_amdgcn_global_load_lds(
      (const __attribute__((address_space(1))) void*)g,
      (__attribute__((address_space(3))) void*)l, 16, 0, 0);
}

// ============================ PREP KERNEL =============================
// Qb,Kb: int8 sign(x)*sign(bq/bk) in [B][T][D].  Vt: bf16 x*sign(bv) in [B][D][T].
__global__ __launch_bounds__(256) void prep_kernel(
    const float* __restrict__ x, const float* __restrict__ bvq,
    const float* __restrict__ bvk, const float* __restrict__ bvv,
    char* __restrict__ Qb, char* __restrict__ Kb, ushort* __restrict__ Vt) {
  __shared__ ushort vt[64][72];
  const int bid = blockIdx.x;
  const int dt = bid & 15;
  const int tt = (bid >> 4) & 31;
  const int b = bid >> 9;
  const int t0 = tt * 64, d0 = dt * 64;
  const int tid = threadIdx.x;

#pragma unroll
  for (int p = 0; p < 4; ++p) {
    const int row = p * 16 + (tid >> 4);
    const int c4 = tid & 15;
    const size_t idx = ((size_t)(b * T_SZ + t0 + row)) * D_SZ + d0 + c4 * 4;
    float4 v = *(const float4*)(x + idx);
    float4 q = *(const float4*)(bvq + d0 + c4 * 4);
    float4 k = *(const float4*)(bvk + d0 + c4 * 4);
    float4 s = *(const float4*)(bvv + d0 + c4 * 4);
    uint32_t xu[4] = {__float_as_uint(v.x), __float_as_uint(v.y),
                      __float_as_uint(v.z), __float_as_uint(v.w)};
    uint32_t qu[4] = {__float_as_uint(q.x), __float_as_uint(q.y),
                      __float_as_uint(q.z), __float_as_uint(q.w)};
    uint32_t ku[4] = {__float_as_uint(k.x), __float_as_uint(k.y),
                      __float_as_uint(k.z), __float_as_uint(k.w)};
    uint32_t su[4] = {__float_as_uint(s.x), __float_as_uint(s.y),
                      __float_as_uint(s.z), __float_as_uint(s.w)};
    uint32_t qw = 0, kw = 0;
#pragma unroll
    for (int j = 0; j < 4; ++j) {
      uint32_t qb = ((xu[j] ^ qu[j]) & 0x80000000u) ? 0xFFu : 0x01u;
      uint32_t kb = ((xu[j] ^ ku[j]) & 0x80000000u) ? 0xFFu : 0x01u;
      qw |= qb << (8 * j);
      kw |= kb << (8 * j);
      vt[row][c4 * 4 + j] = f2bf(__uint_as_float(xu[j] ^ (su[j] & 0x80000000u)));
    }
    *(uint32_t*)(Qb + idx) = qw;
    *(uint32_t*)(Kb + idx) = kw;
  }
  __syncthreads();
#pragma unroll
  for (int p = 0; p < 2; ++p) {
    const int dr = p * 32 + (tid >> 3);
    const int tc = tid & 7;
    ushort8 o;
#pragma unroll
    for (int j = 0; j < 8; ++j) o[j] = vt[tc * 8 + j][dr];
    *(ushort8*)(Vt + ((size_t)(b * D_SZ + d0 + dr)) * T_SZ + t0 + tc * 8) = o;
  }
}

// ============================ SCORE KERNEL ============================
// 128x128 tile per block, 8 waves (wave = 32q x 64s), BK=128, double-buffered
// LDS. 1D grid 544, remapped so each XCD pair-of-b keeps Qb/Kb[b] L2-resident:
// bid = 8*(j>>1) + 2*b + (j&1).
__global__ __launch_bounds__(NTH) void score_kernel(
    const char* __restrict__ Qb, const char* __restrict__ Kb,
    ushort* __restrict__ P) {
  __shared__ __align__(16) unsigned char Qs[2][128 * 128];  // 32 KB
  __shared__ __align__(16) unsigned char Ks[2][128 * 128];  // 32 KB

  const int bid = blockIdx.x;
  const int xcd = bid & 7;
  const int b = xcd >> 1;
  const int j = ((bid >> 3) << 1) + (xcd & 1);
  int qt = (int)((sqrtf(8.f * (float)j + 1.f) - 1.f) * 0.5f);
  while ((qt + 1) * (qt + 2) / 2 <= j) ++qt;
  while (qt * (qt + 1) / 2 > j) --qt;
  const int st = j - qt * (qt + 1) / 2;

  const int tid = threadIdx.x;
  const int lane = tid & 63, w = tid >> 6;
  const int wr = w >> 1, wc = w & 1;
  const int l15 = lane & 15, l4 = lane >> 4;

  const size_t qrow0 = ((size_t)(b * T_SZ + qt * 128)) * D_SZ;
  const size_t krow0 = ((size_t)(b * T_SZ + st * 128)) * D_SZ;

  i32x4 sacc[2][4];
#pragma unroll
  for (int mf = 0; mf < 2; ++mf)
#pragma unroll
    for (int nf = 0; nf < 4; ++nf) sacc[mf][nf] = (i32x4){0, 0, 0, 0};

  auto STAGE = [&](int buf, int ks) {
#pragma unroll
    for (int i = 0; i < 4; ++i) {
      const int isK = i >> 1;
      const int fi = tid + (i & 1) * 512;
      const int row = fi >> 3, c = fi & 7;
      const int cs = c ^ (row & 7);
      const char* src = (isK ? Kb + krow0 : Qb + qrow0) +
                        (size_t)row * D_SZ + ks * 128 + cs * 16;
      unsigned char* dst = (isK ? Ks[buf] : Qs[buf]) + fi * 16;
      glds16(src, dst);
    }
  };

  STAGE(0, 0);
  for (int ks = 0; ks < 8; ++ks) {
    asm volatile("s_waitcnt vmcnt(0)" ::: "memory");
    __builtin_amdgcn_s_barrier();
    if (ks + 1 < 8) STAGE((ks + 1) & 1, ks + 1);
    const int buf = ks & 1;
#pragma unroll
    for (int kc = 0; kc < 2; ++kc) {
      i32x4 af[2], bfr[4];
#pragma unroll
      for (int mf = 0; mf < 2; ++mf) {
        const int row = wr * 32 + mf * 16 + l15;
        const int ch = (kc * 4 + l4) ^ (row & 7);
        af[mf] = *(const i32x4*)(Qs[buf] + row * 128 + ch * 16);
      }
#pragma unroll
      for (int nf = 0; nf < 4; ++nf) {
        const int row = wc * 64 + nf * 16 + l15;
        const int ch = (kc * 4 + l4) ^ (row & 7);
        bfr[nf] = *(const i32x4*)(Ks[buf] + row * 128 + ch * 16);
      }
#pragma unroll
      for (int mf = 0; mf < 2; ++mf)
#pragma unroll
        for (int nf = 0; nf < 4; ++nf)
          sacc[mf][nf] = __builtin_amdgcn_mfma_i32_16x16x64_i8(
              af[mf], bfr[nf], sacc[mf][nf], 0, 0, 0);
    }
    asm volatile("s_waitcnt lgkmcnt(0)" ::: "memory");
  }

  // sigmoid + causal mask + write
#pragma unroll
  for (int mf = 0; mf < 2; ++mf)
#pragma unroll
    for (int nf = 0; nf < 4; ++nf)
#pragma unroll
      for (int r = 0; r < 4; ++r) {
        const int qg = qt * 128 + wr * 32 + mf * 16 + l4 * 4 + r;
        const int sg = st * 128 + wc * 64 + nf * 16 + l15;
        float p = 1.f / (1.f + __expf(-0.125f * (float)sacc[mf][nf][r]));
        if (sg > qg) p = 0.f;
        P[((size_t)(b * T_SZ + qg)) * T_SZ + sg] = f2bf(p);
      }
}

// ============================== PV KERNEL =============================
// out[b][q][d] = sum_s P[q][s] * Vt[d][s].  Block = 64q x 256d, BK=64s,
// pair (pr,31-pr) -> 33 uniform steps. Triple-buffer, distance-2 prefetch,
// counted vmcnt. XCD remap: bid = xcd + 8*(pr + 16*pg), g=(b,ds)=xcd+8*pg,
// so all 16 same-(b,ds) blocks share one XCD -> V slice (1MB) L2-resident.
__global__ __launch_bounds__(NTH) void pv_kernel(
    const ushort* __restrict__ P, const ushort* __restrict__ Vt,
    float* __restrict__ out) {
  __shared__ __align__(16) unsigned char Pl[3][64 * 128];    // 24 KB
  __shared__ __align__(16) unsigned char Vl[3][256 * 128];   // 96 KB
  const int bid = blockIdx.x;
  const int xcd = bid & 7;
  const int rr = bid >> 3;
  const int pr = rr & 15;
  const int pg = rr >> 4;
  const int g = xcd + 8 * pg;  // 0..15
  const int b = g >> 2;
  const int ds = g & 3;

  const int tid = threadIdx.x;
  const int lane = tid & 63, w = tid >> 6;
  const int wr = w >> 2, dg = w & 3;
  const int l15 = lane & 15, l4 = lane >> 4;

  const char* Pb = (const char*)P;
  const char* Vb = (const char*)Vt;
  const size_t vrow0 = ((size_t)(b * D_SZ + ds * 256)) * (T_SZ * 2);

  for (int half = 0; half < 2; ++half) {
    const int qt = half ? (31 - pr) : pr;
    const int nst = qt + 1;
    const size_t prow0 = ((size_t)(b * T_SZ + qt * 64)) * (T_SZ * 2);

    // stage s-tile stt (64 s-cols): 1 P chunk + 4 V chunks per thread
    auto STAGE = [&](int buf, int stt) {
      {
        const int row = tid >> 3, c = tid & 7;
        const int cs = c ^ (row & 7);
        glds16(Pb + prow0 + (size_t)row * (T_SZ * 2) + stt * 128 + cs * 16,
               Pl[buf] + tid * 16);
      }
#pragma unroll
      for (int i = 0; i < 4; ++i) {
        const int f = tid + i * 512;
        const int row = f >> 3, c = f & 7;
        const int cs = c ^ (row & 7);
        glds16(Vb + vrow0 + (size_t)row * (T_SZ * 2) + stt * 128 + cs * 16,
               Vl[buf] + f * 16);
      }
    };

    if (half) __builtin_amdgcn_s_barrier();  // all waves done with buffers

    f32x4 acc[2][4];
#pragma unroll
    for (int mf = 0; mf < 2; ++mf)
#pragma unroll
      for (int nf = 0; nf < 4; ++nf) acc[mf][nf] = (f32x4){0.f, 0.f, 0.f, 0.f};

    STAGE(0, 0);
    if (nst > 1) STAGE(1, 1);

    for (int t = 0; t < nst; ++t) {
      if (t + 1 < nst)
        asm volatile("s_waitcnt vmcnt(5)" ::: "memory");  // tile t landed
      else
        asm volatile("s_waitcnt vmcnt(0)" ::: "memory");
      __builtin_amdgcn_s_barrier();
      if (t + 2 < nst) STAGE((t + 2) % 3, t + 2);
      const int buf = t % 3;
#pragma unroll
      for (int kk = 0; kk < 2; ++kk) {
        bf16x8 pa[2], vb[4];
#pragma unroll
        for (int mf = 0; mf < 2; ++mf) {
          const int row = wr * 32 + mf * 16 + l15;
          const int ch = (kk * 4 + l4) ^ (row & 7);
          pa[mf] = *(const bf16x8*)(Pl[buf] + row * 128 + ch * 16);
        }
#pragma unroll
        for (int nf = 0; nf < 4; ++nf) {
          const int row = dg * 64 + nf * 16 + l15;
          const int ch = (kk * 4 + l4) ^ (row & 7);
          vb[nf] = *(const bf16x8*)(Vl[buf] + row * 128 + ch * 16);
        }
#pragma unroll
        for (int mf = 0; mf < 2; ++mf)
#pragma unroll
          for (int nf = 0; nf < 4; ++nf)
            acc[mf][nf] = __builtin_amdgcn_mfma_f32_16x16x32_bf16(
                pa[mf], vb[nf], acc[mf][nf], 0, 0, 0);
      }
      asm volatile("s_waitcnt lgkmcnt(0)" ::: "memory");  // reads drained
    }

    float* ob = out + ((size_t)(b * T_SZ + qt * 64 + wr * 32)) * D_SZ +
                ds * 256 + dg * 64;
#pragma unroll
    for (int mf = 0; mf < 2; ++mf)
#pragma unroll
      for (int nf = 0; nf < 4; ++nf)
#pragma unroll
        for (int r = 0; r < 4; ++r)
          ob[(size_t)(mf * 16 + l4 * 4 + r) * D_SZ + nf * 16 + l15] =
              acc[mf][nf][r];
  }
}

// =================== MID FALLBACK (R2 attn_main, 32MB ws) =============
__global__ __launch_bounds__(NTH, 4) void attn_main(
    const char* __restrict__ Qb, const char* __restrict__ Kb,
    const ushort* __restrict__ Vt, float* __restrict__ out) {
  __shared__ __align__(16) unsigned char Qs[32][1040];
  __shared__ __align__(16) ushort Ps[32][72];
  const int tid = threadIdx.x;
  const int lane = tid & 63;
  const int w = tid >> 6;
  const int rg = w >> 2, cg = w & 3;
  const int l15 = lane & 15, l4 = lane >> 4;
  const int bid = blockIdx.x;
  const int half = bid & 1;
  const int ti = (bid >> 1) & 63;
  const int b = bid >> 7;
  const int t0 = ti * 32;
  {
    const int row = tid >> 4;
    const int c = (tid & 15) * 64;
    const uint4* src = (const uint4*)(Qb + ((size_t)(b * T_SZ + t0 + row)) * D_SZ + c);
    uint4 a0 = src[0], a1 = src[1], a2 = src[2], a3 = src[3];
    *(uint4*)&Qs[row][c] = a0;
    *(uint4*)&Qs[row][c + 16] = a1;
    *(uint4*)&Qs[row][c + 32] = a2;
    *(uint4*)&Qs[row][c + 48] = a3;
  }
  __syncthreads();
  const int nt = (t0 + 32 + 63) / 64;
  const int s_beg = half ? (nt + 1) / 2 : 0;
  const int s_end = half ? nt : (nt + 1) / 2;
  f32x4 acc[16];
#pragma unroll
  for (int f = 0; f < 16; ++f) acc[f] = (f32x4){0.f, 0.f, 0.f, 0.f};
  const unsigned char* qrow = &Qs[rg * 16 + l15][l4 * 16];
  for (int st = s_beg; st < s_end; ++st) {
    const int s0 = st * 64;
    i32x4 sacc = (i32x4){0, 0, 0, 0};
    const char* kbase = Kb + ((size_t)(b * T_SZ + s0 + cg * 16 + l15)) * D_SZ + l4 * 16;
#pragma unroll
    for (int kc = 0; kc < 16; ++kc) {
      i32x4 a = *(const i32x4*)(qrow + kc * 64);
      i32x4 kf = *(const i32x4*)(kbase + kc * 64);
      sacc = __builtin_amdgcn_mfma_i32_16x16x64_i8(a, kf, sacc, 0, 0, 0);
    }
    __syncthreads();
    {
      const int scol = cg * 16 + l15;
      const int sg = s0 + scol;
#pragma unroll
      for (int r = 0; r < 4; ++r) {
        const int m = rg * 16 + l4 * 4 + r;
        float p = 0.f;
        if (sg <= t0 + m) p = 1.f / (1.f + __expf(-0.125f * (float)sacc[r]));
        Ps[m][scol] = f2bf(p);
      }
    }
    __syncthreads();
    const ushort* vtb = Vt + ((size_t)(b * D_SZ + cg * 256)) * T_SZ + s0;
#pragma unroll
    for (int kk = 0; kk < 2; ++kk) {
      bf16x8 pa = *(const bf16x8*)&Ps[rg * 16 + l15][kk * 32 + l4 * 8];
      const ushort* vks = vtb + kk * 32 + l4 * 8;
#pragma unroll
      for (int f = 0; f < 16; ++f) {
        bf16x8 vb = *(const bf16x8*)(vks + (size_t)(f * 16 + l15) * T_SZ);
        acc[f] = __builtin_amdgcn_mfma_f32_16x16x32_bf16(pa, vb, acc[f], 0, 0, 0);
      }
    }
  }
  float* orow = out + ((size_t)(b * T_SZ + t0)) * D_SZ;
#pragma unroll
  for (int f = 0; f < 16; ++f) {
    const int n = cg * 256 + f * 16 + l15;
#pragma unroll
    for (int r = 0; r < 4; ++r) {
      const int m = rg * 16 + l4 * 4 + r;
      atomicAdd(orow + (size_t)m * D_SZ + n, acc[f][r]);
    }
  }
}

// ===================== BASE FALLBACK (no ws needed) ===================
__global__ __launch_bounds__(NTH) void hdc_attn_fallback(
    const float* __restrict__ x, const float* __restrict__ bvq,
    const float* __restrict__ bvk, const float* __restrict__ bvv,
    float* __restrict__ out) {
  __shared__ ushort Qs[32][1032];
  __shared__ ushort Ks[64][72];
  __shared__ ushort Ps[32][72];
  const int tid = threadIdx.x;
  const int lane = tid & 63;
  const int w = tid >> 6;
  const int rg = w >> 2, cg = w & 3;
  const int l15 = lane & 15, l4 = lane >> 4;
  const int b = blockIdx.x >> 6;
  const int ti = blockIdx.x & 63;
  const int t0 = ti * 32;
  {
    const float4* xr = (const float4*)(x + ((size_t)b * T_SZ + t0) * D_SZ);
    const float4* bq4 = (const float4*)bvq;
#pragma unroll
    for (int i = 0; i < 16; ++i) {
      int flat4 = tid + i * NTH;
      int row = flat4 >> 8, c4 = flat4 & 255;
      float4 v = xr[row * 256 + c4];
      float4 q = bq4[c4];
      uint32_t q0 = sbf(__float_as_uint(v.x), __float_as_uint(q.x));
      uint32_t q1 = sbf(__float_as_uint(v.y), __float_as_uint(q.y));
      uint32_t q2 = sbf(__float_as_uint(v.z), __float_as_uint(q.z));
      uint32_t q3 = sbf(__float_as_uint(v.w), __float_as_uint(q.w));
      *(uint2*)&Qs[row][c4 * 4] = make_uint2(q0 | (q1 << 16), q2 | (q3 << 16));
    }
  }
  uint32_t vsign[16];
#pragma unroll
  for (int f = 0; f < 16; ++f)
    vsign[f] = __float_as_uint(bvv[cg * 256 + f * 16 + l15]) & 0x80000000u;
  f32x4 acc[16];
#pragma unroll
  for (int f = 0; f < 16; ++f) acc[f] = (f32x4){0.f, 0.f, 0.f, 0.f};
  const int nt = (t0 + 32 + 63) / 64;
  for (int st = 0; st < nt; ++st) {
    const int s0 = st * 64;
    f32x4 sacc = (f32x4){0.f, 0.f, 0.f, 0.f};
    for (int dc = 0; dc < D_SZ / 64; ++dc) {
      __syncthreads();
      {
        const int s = tid >> 3;
        const int c8 = (tid & 7) * 8;
        const float* xk = x + ((size_t)b * T_SZ + s0 + s) * D_SZ + dc * 64 + c8;
        const float* bk = bvk + dc * 64 + c8;
        float4 v0 = *(const float4*)xk;
        float4 v1 = *(const float4*)(xk + 4);
        float4 k0 = *(const float4*)bk;
        float4 k1 = *(const float4*)(bk + 4);
        uint32_t w0 = sbf(__float_as_uint(v0.x), __float_as_uint(k0.x)) |
                      (sbf(__float_as_uint(v0.y), __float_as_uint(k0.y)) << 16);
        uint32_t w1 = sbf(__float_as_uint(v0.z), __float_as_uint(k0.z)) |
                      (sbf(__float_as_uint(v0.w), __float_as_uint(k0.w)) << 16);
        uint32_t w2 = sbf(__float_as_uint(v1.x), __float_as_uint(k1.x)) |
                      (sbf(__float_as_uint(v1.y), __float_as_uint(k1.y)) << 16);
        uint32_t w3 = sbf(__float_as_uint(v1.z), __float_as_uint(k1.z)) |
                      (sbf(__float_as_uint(v1.w), __float_as_uint(k1.w)) << 16);
        *(uint4*)&Ks[s][c8] = make_uint4(w0, w1, w2, w3);
      }
      __syncthreads();
#pragma unroll
      for (int h = 0; h < 2; ++h) {
        bf16x8 a = *(const bf16x8*)&Qs[rg * 16 + l15][dc * 64 + h * 32 + l4 * 8];
        bf16x8 kb = *(const bf16x8*)&Ks[cg * 16 + l15][h * 32 + l4 * 8];
        sacc = __builtin_amdgcn_mfma_f32_16x16x32_bf16(a, kb, sacc, 0, 0, 0);
      }
    }
    {
      const int scol = cg * 16 + l15;
      const int sg = s0 + scol;
#pragma unroll
      for (int r = 0; r < 4; ++r) {
        const int m = rg * 16 + l4 * 4 + r;
        float p = 0.f;
        if (sg <= t0 + m) p = 1.f / (1.f + __expf(-0.125f * sacc[r]));
        Ps[m][scol] = (ushort)(__float_as_uint(p) >> 16);
      }
    }
    __syncthreads();
    const float* xv = x + ((size_t)b * T_SZ + s0) * D_SZ;
#pragma unroll
    for (int kk = 0; kk < 2; ++kk) {
      bf16x8 pa = *(const bf16x8*)&Ps[rg * 16 + l15][kk * 32 + l4 * 8];
      const float* xvs = xv + (size_t)(kk * 32 + l4 * 8) * D_SZ;
#pragma unroll
      for (int f = 0; f < 16; ++f) {
        const int n = cg * 256 + f * 16 + l15;
        const float* xn = xvs + n;
        bf16x8 vb;
#pragma unroll
        for (int i = 0; i < 8; ++i) {
          uint32_t u = __float_as_uint(xn[(size_t)i * D_SZ]) ^ vsign[f];
          vb[i] = (short)(u >> 16);
        }
        acc[f] = __builtin_amdgcn_mfma_f32_16x16x32_bf16(pa, vb, acc[f], 0, 0, 0);
      }
    }
  }
  float* orow = out + ((size_t)b * T_SZ + t0) * D_SZ;
#pragma unroll
  for (int f = 0; f < 16; ++f) {
    const int n = cg * 256 + f * 16 + l15;
#pragma unroll
    for (int r = 0; r < 4; ++r) {
      const int m = rg * 16 + l4 * 4 + r;
      orow[(size_t)m * D_SZ + n] = acc[f][r];
    }
  }
}

extern "C" void kernel_launch(void* const* d_in, const int* in_sizes, int n_in,
                              void* d_out, int out_size, void* d_ws, size_t ws_size,
                              hipStream_t stream) {
  const float* x = (const float*)d_in[0];
  const float* bvq = (const float*)d_in[1];
  const float* bvk = (const float*)d_in[2];
  const float* bvv = (const float*)d_in[3];
  float* out = (float*)d_out;

  const size_t QB_SZ = (size_t)B_SZ * T_SZ * D_SZ;     // 8 MB (i8)
  const size_t VT_SZ = QB_SZ * 2;                      // 16 MB (bf16)
  const size_t P_SZ = (size_t)B_SZ * T_SZ * T_SZ * 2;  // 32 MB (bf16)
  const size_t NEED_MID = QB_SZ * 2 + VT_SZ;           // 32 MB
  const size_t NEED_FULL = NEED_MID + P_SZ;            // 64 MB

  if (ws_size >= NEED_MID) {
    char* Qb = (char*)d_ws;
    char* Kb = Qb + QB_SZ;
    ushort* Vt = (ushort*)(Kb + QB_SZ);
    hipLaunchKernelGGL(prep_kernel, dim3(B_SZ * 32 * 16), dim3(256), 0, stream,
                       x, bvq, bvk, bvv, Qb, Kb, Vt);
    if (ws_size >= NEED_FULL) {
      ushort* P = (ushort*)((char*)d_ws + NEED_MID);
      hipLaunchKernelGGL(score_kernel, dim3(544), dim3(NTH), 0, stream,
                         Qb, Kb, P);
      hipLaunchKernelGGL(pv_kernel, dim3(256), dim3(NTH), 0, stream,
                         P, Vt, out);
    } else {
      hipMemsetAsync(out, 0, (size_t)out_size * sizeof(float), stream);
      hipLaunchKernelGGL(attn_main, dim3(B_SZ * 64 * 2), dim3(NTH), 0, stream,
                         Qb, Kb, Vt, out);
    }
  } else {
    hipLaunchKernelGGL(hdc_attn_fallback, dim3(B_SZ * 64), dim3(NTH), 0, stream,
                       x, bvq, bvk, bvv, out);
  }
}